// Round 9
// baseline (663.942 us; speedup 1.0000x reference)
//
#include <hip/hip_runtime.h>
#include <hip/hip_bf16.h>

// EfficientTransformerEncoder: B=32, D=256, L=1024, NH=8, DH=32, WIN=64, DFF=1024, NL=3.
// Inputs fp32. bf16 tensors in k-chunk-major layout T[k/8][row][8] (register-direct
// MFMA frags). FFN1+GELU+FFN2+resid+LN fused in one kernel (H lives in LDS).
#define BSZ 32
#define DM 256
#define LSEQ 1024
#define MTOK (BSZ * LSEQ)   // 32768 tokens
#define NHEAD 8
#define DHEAD 32
#define WIN 64
#define DFF 1024
#define M8 ((size_t)MTOK * 8)   // chunk stride (shorts) for M-row activations

typedef short bf16x8 __attribute__((ext_vector_type(8)));
typedef float f32x4 __attribute__((ext_vector_type(4)));
typedef unsigned short u16x8 __attribute__((ext_vector_type(8)));

union BF { __hip_bfloat16 h; unsigned short u; };
__device__ __forceinline__ unsigned short f2bf(float f) { BF b; b.h = __float2bfloat16(f); return b.u; }
__device__ __forceinline__ float bf2f(unsigned short u) { return __uint_as_float((unsigned)u << 16); }
// cheap pack: round-half-up to bf16, pack two -> u32 (0.5 ulp, ~5 VALU/pair)
__device__ __forceinline__ unsigned pk2bf(float a, float b) {
    unsigned ua = __float_as_uint(a) + 0x8000u;
    unsigned ub = __float_as_uint(b) + 0x8000u;
    return (ua >> 16) | (ub & 0xffff0000u);
}

#define GLD_LDS16(gp, lp) __builtin_amdgcn_global_load_lds( \
    (const __attribute__((address_space(1))) void*)(gp),    \
    (__attribute__((address_space(3))) void*)(lp), 16, 0, 0)

// tanh-form GELU (validated round 7)
__device__ __forceinline__ float gelu_fast(float x) {
    float t = x * (0.7978845608f + 0.0356774081f * x * x);
    return x / (1.0f + __expf(-2.0f * t));
}

// ------------------------------------------------------------- weight cvt --
// fp32 [nl][N][K] row-major -> bf16 [nl][K/8][N][8]
__global__ __launch_bounds__(256) void cvt_kernel(
    const float* __restrict__ s, unsigned short* __restrict__ d,
    int N, int K, int nl)
{
    int K8 = K >> 3;
    int per = N * K8;
    int c = blockIdx.x * 256 + threadIdx.x;
    if (c >= per * nl) return;
    int layer = c / per, rem = c - layer * per;
    int n = rem / K8, kc = rem - n * K8;
    const float* sp = s + (size_t)layer * N * K + (size_t)n * K + kc * 8;
    float4 v0 = *(const float4*)sp, v1 = *(const float4*)(sp + 4);
    uint4 o = { pk2bf(v0.x, v0.y), pk2bf(v0.z, v0.w),
                pk2bf(v1.x, v1.y), pk2bf(v1.z, v1.w) };
    *(uint4*)(d + (size_t)layer * N * K + (size_t)kc * N * 8 + (size_t)n * 8) = o;
}

// -------------------------------------------------------------- PE table ---
__global__ __launch_bounds__(256) void pe_kernel(float* __restrict__ PE)
{
    int l = blockIdx.x, c = threadIdx.x;
    int i2 = c & ~1;
    float div = expf(-9.210340371976184f * (float)i2 / 256.0f);  // -ln(10000)
    float ang = (float)l * div;
    PE[l * DM + c] = (c & 1) ? cosf(ang) : sinf(ang);
}

// ---------------------------------------------------------------- embed ----
__global__ __launch_bounds__(256) void embed_kernel(
    const float* __restrict__ F, const float* __restrict__ PE,
    float* __restrict__ Xf, unsigned short* __restrict__ Xb)
{
    __shared__ float tile[64][65];
    int b = blockIdx.z, l0 = blockIdx.y * 64, c0 = blockIdx.x * 64;
    int tid = threadIdx.x;
    int li = tid & 63, c4 = tid >> 6;
    #pragma unroll
    for (int it = 0; it < 16; ++it) {
        int c = c4 + it * 4;
        tile[c][li] = F[((size_t)(b * DM + c0 + c)) * LSEQ + l0 + li];
    }
    __syncthreads();
    int ci = tid & 63, l4 = tid >> 6;
    #pragma unroll
    for (int it = 0; it < 16; ++it) {
        int l = l4 + it * 4;
        float x = tile[ci][l] + PE[(l0 + l) * DM + c0 + ci];
        Xf[((size_t)b * LSEQ + l0 + l) * DM + c0 + ci] = x;
    }
    int ch = tid >> 5;          // chunk within c0-range (0..7)
    int lx = tid & 31;
    #pragma unroll
    for (int rd = 0; rd < 2; ++rd) {
        int l = lx + rd * 32;
        float vs[8];
        #pragma unroll
        for (int e = 0; e < 8; ++e) {
            int c = ch * 8 + e;
            vs[e] = tile[c][l] + PE[(l0 + l) * DM + c0 + c];
        }
        uint4 o = { pk2bf(vs[0], vs[1]), pk2bf(vs[2], vs[3]),
                    pk2bf(vs[4], vs[5]), pk2bf(vs[6], vs[7]) };
        *(uint4*)(Xb + ((size_t)((c0 >> 3) + ch)) * M8 +
                  (size_t)(b * LSEQ + l0 + l) * 8) = o;
    }
}

// ----------------------------------------------- register-direct MFMA gemm --
// Used for QKV. Cb[nc][m][8] = A[kc][m][8] @ Bw[kc][n][8] + bias[n].
__global__ __launch_bounds__(256) void gemm_mfma_kernel(
    const unsigned short* __restrict__ A, const unsigned short* __restrict__ Bw,
    const float* __restrict__ bias, unsigned short* __restrict__ Cb,
    int M, int N, int K)
{
    __shared__ __align__(16) char smem[17408];      // epilogue transpose only
    const int tid = threadIdx.x;
    const int lane = tid & 63, wave = tid >> 6;
    const int l15 = lane & 15, quad = lane >> 4;
    const int wm = (wave & 1) * 64, wn = (wave >> 1) * 64;
    const int m0 = blockIdx.x * 128, n0 = blockIdx.y * 128;
    const size_t Ma8 = (size_t)M * 8, Nb8 = (size_t)N * 8;
    const size_t astep = 4 * Ma8, bstep = 4 * Nb8;

    const unsigned short* ap[4];
    const unsigned short* bp[4];
    #pragma unroll
    for (int i = 0; i < 4; ++i)
        ap[i] = A + quad * Ma8 + (size_t)(m0 + wm + i * 16 + l15) * 8;
    #pragma unroll
    for (int j = 0; j < 4; ++j)
        bp[j] = Bw + quad * Nb8 + (size_t)(n0 + wn + j * 16 + l15) * 8;

    f32x4 acc[4][4] = {};
    bf16x8 aA[4], bA[4], aB[4], bB[4];
    #pragma unroll
    for (int i = 0; i < 4; ++i) aA[i] = *(const bf16x8*)(ap[i]);
    #pragma unroll
    for (int j = 0; j < 4; ++j) bA[j] = *(const bf16x8*)(bp[j]);

    const int iters = K >> 5;
    for (int t = 0; t < iters; t += 2) {
        size_t o1 = (size_t)(t + 1);
        #pragma unroll
        for (int i = 0; i < 4; ++i) aB[i] = *(const bf16x8*)(ap[i] + o1 * astep);
        #pragma unroll
        for (int j = 0; j < 4; ++j) bB[j] = *(const bf16x8*)(bp[j] + o1 * bstep);
        #pragma unroll
        for (int i = 0; i < 4; ++i)
            #pragma unroll
            for (int j = 0; j < 4; ++j)
                acc[i][j] = __builtin_amdgcn_mfma_f32_16x16x32_bf16(
                    aA[i], bA[j], acc[i][j], 0, 0, 0);
        size_t o2 = (size_t)((t + 2 < iters) ? t + 2 : iters - 1);
        #pragma unroll
        for (int i = 0; i < 4; ++i) aA[i] = *(const bf16x8*)(ap[i] + o2 * astep);
        #pragma unroll
        for (int j = 0; j < 4; ++j) bA[j] = *(const bf16x8*)(bp[j] + o2 * bstep);
        #pragma unroll
        for (int i = 0; i < 4; ++i)
            #pragma unroll
            for (int j = 0; j < 4; ++j)
                acc[i][j] = __builtin_amdgcn_mfma_f32_16x16x32_bf16(
                    aB[i], bB[j], acc[i][j], 0, 0, 0);
    }

    float* Es = (float*)(smem + wave * 4352);   // 16 x 68 floats
    const int r16 = lane >> 2;
    const int cg  = (lane & 3) * 16;
    const int nb = n0 + wn + cg;
    float bb[16];
    #pragma unroll
    for (int c = 0; c < 4; ++c) {              // hoisted bias loads
        float4 b4 = *(const float4*)(bias + nb + c * 4);
        bb[c * 4 + 0] = b4.x; bb[c * 4 + 1] = b4.y;
        bb[c * 4 + 2] = b4.z; bb[c * 4 + 3] = b4.w;
    }
    #pragma unroll
    for (int i = 0; i < 4; ++i) {
        #pragma unroll
        for (int j = 0; j < 4; ++j)
            #pragma unroll
            for (int r = 0; r < 4; ++r)
                Es[(quad * 4 + r) * 68 + j * 16 + l15] = acc[i][j][r];
        asm volatile("s_waitcnt lgkmcnt(0)" ::: "memory");

        int m = m0 + wm + i * 16 + r16;
        float v[16];
        #pragma unroll
        for (int c = 0; c < 4; ++c) {
            f32x4 t = *(const f32x4*)&Es[r16 * 68 + cg + c * 4];
            v[c * 4 + 0] = t[0] + bb[c * 4 + 0];
            v[c * 4 + 1] = t[1] + bb[c * 4 + 1];
            v[c * 4 + 2] = t[2] + bb[c * 4 + 2];
            v[c * 4 + 3] = t[3] + bb[c * 4 + 3];
        }
        size_t gb = ((size_t)(nb >> 3)) * Ma8 + (size_t)m * 8;
        #pragma unroll
        for (int c = 0; c < 2; ++c) {
            uint4 o = { pk2bf(v[c*8+0], v[c*8+1]), pk2bf(v[c*8+2], v[c*8+3]),
                        pk2bf(v[c*8+4], v[c*8+5]), pk2bf(v[c*8+6], v[c*8+7]) };
            *(uint4*)(Cb + gb + (size_t)c * Ma8) = o;
        }
        asm volatile("" ::: "memory");
    }
}

// --------------------------------- register-direct MFMA gemm + fused LN ----
// Used for attention out-proj. X = LN(A@Bw^T + bias + resid) -> Xf + Xb.
__global__ __launch_bounds__(256) void gemm_ln_kernel(
    const unsigned short* __restrict__ A, const unsigned short* __restrict__ Bw,
    const float* __restrict__ bias, const float* __restrict__ resid,
    const float* __restrict__ lns, const float* __restrict__ lnb,
    float* __restrict__ Xf, unsigned short* __restrict__ Xb, int K)
{
    __shared__ __align__(16) char smem[17408];
    __shared__ float Ss[256], Sq[256];
    const int tid = threadIdx.x;
    const int lane = tid & 63, wave = tid >> 6;
    const int l15 = lane & 15, quad = lane >> 4;
    const int wn = wave * 64;
    const int m0 = blockIdx.x * 64;
    const size_t Nb8 = (size_t)DM * 8;
    const size_t astep = 4 * M8, bstep = 4 * Nb8;

    const unsigned short* ap[4];
    const unsigned short* bp[4];
    #pragma unroll
    for (int i = 0; i < 4; ++i)
        ap[i] = A + quad * M8 + (size_t)(m0 + i * 16 + l15) * 8;
    #pragma unroll
    for (int j = 0; j < 4; ++j)
        bp[j] = Bw + quad * Nb8 + (size_t)(wn + j * 16 + l15) * 8;

    f32x4 acc[4][4] = {};
    bf16x8 aA[4], bA[4], aB[4], bB[4];
    #pragma unroll
    for (int i = 0; i < 4; ++i) aA[i] = *(const bf16x8*)(ap[i]);
    #pragma unroll
    for (int j = 0; j < 4; ++j) bA[j] = *(const bf16x8*)(bp[j]);

    const int iters = K >> 5;
    for (int t = 0; t < iters; t += 2) {
        size_t o1 = (size_t)(t + 1);
        #pragma unroll
        for (int i = 0; i < 4; ++i) aB[i] = *(const bf16x8*)(ap[i] + o1 * astep);
        #pragma unroll
        for (int j = 0; j < 4; ++j) bB[j] = *(const bf16x8*)(bp[j] + o1 * bstep);
        #pragma unroll
        for (int i = 0; i < 4; ++i)
            #pragma unroll
            for (int j = 0; j < 4; ++j)
                acc[i][j] = __builtin_amdgcn_mfma_f32_16x16x32_bf16(
                    aA[i], bA[j], acc[i][j], 0, 0, 0);
        size_t o2 = (size_t)((t + 2 < iters) ? t + 2 : iters - 1);
        #pragma unroll
        for (int i = 0; i < 4; ++i) aA[i] = *(const bf16x8*)(ap[i] + o2 * astep);
        #pragma unroll
        for (int j = 0; j < 4; ++j) bA[j] = *(const bf16x8*)(bp[j] + o2 * bstep);
        #pragma unroll
        for (int i = 0; i < 4; ++i)
            #pragma unroll
            for (int j = 0; j < 4; ++j)
                acc[i][j] = __builtin_amdgcn_mfma_f32_16x16x32_bf16(
                    aB[i], bB[j], acc[i][j], 0, 0, 0);
    }

    float bj[4], scj[4], bbj[4];
    #pragma unroll
    for (int j = 0; j < 4; ++j) {
        int col = wn + j * 16 + l15;
        bj[j] = bias[col]; scj[j] = lns[col]; bbj[j] = lnb[col];
    }
    #pragma unroll
    for (int i = 0; i < 4; ++i)
        #pragma unroll
        for (int r = 0; r < 4; ++r) {
            const float* rp = resid + (size_t)(m0 + i * 16 + quad * 4 + r) * DM + wn;
            #pragma unroll
            for (int j = 0; j < 4; ++j)
                acc[i][j][r] += bj[j] + rp[j * 16 + l15];
        }

    #pragma unroll
    for (int i = 0; i < 4; ++i)
        #pragma unroll
        for (int r = 0; r < 4; ++r) {
            float s = 0.f, q = 0.f;
            #pragma unroll
            for (int j = 0; j < 4; ++j) {
                float x = acc[i][j][r];
                s += x; q = fmaf(x, x, q);
            }
            #pragma unroll
            for (int off = 1; off < 16; off <<= 1) {
                s += __shfl_xor(s, off);
                q += __shfl_xor(q, off);
            }
            if (l15 == 0) {
                int row = i * 16 + quad * 4 + r;
                Ss[wave * 64 + row] = s;
                Sq[wave * 64 + row] = q;
            }
        }
    __syncthreads();
    #pragma unroll
    for (int i = 0; i < 4; ++i)
        #pragma unroll
        for (int r = 0; r < 4; ++r) {
            int row = i * 16 + quad * 4 + r;
            float s = Ss[row] + Ss[64 + row] + Ss[128 + row] + Ss[192 + row];
            float q = Sq[row] + Sq[64 + row] + Sq[128 + row] + Sq[192 + row];
            float mean = s * (1.0f / 256.0f);
            float var  = q * (1.0f / 256.0f) - mean * mean;
            float rinv = rsqrtf(var + 1e-5f);
            #pragma unroll
            for (int j = 0; j < 4; ++j)
                acc[i][j][r] = (acc[i][j][r] - mean) * rinv * scj[j] + bbj[j];
        }

    float* Es = (float*)(smem + wave * 4352);
    const int r16 = lane >> 2;
    const int cg  = (lane & 3) * 16;
    #pragma unroll
    for (int i = 0; i < 4; ++i) {
        #pragma unroll
        for (int j = 0; j < 4; ++j)
            #pragma unroll
            for (int r = 0; r < 4; ++r)
                Es[(quad * 4 + r) * 68 + j * 16 + l15] = acc[i][j][r];
        asm volatile("s_waitcnt lgkmcnt(0)" ::: "memory");

        int m = m0 + i * 16 + r16;
        float v[16];
        #pragma unroll
        for (int c = 0; c < 4; ++c) {
            f32x4 t = *(const f32x4*)&Es[r16 * 68 + cg + c * 4];
            v[c * 4 + 0] = t[0]; v[c * 4 + 1] = t[1];
            v[c * 4 + 2] = t[2]; v[c * 4 + 3] = t[3];
        }
        size_t gf = (size_t)m * DM + wn + cg;
        #pragma unroll
        for (int c = 0; c < 4; ++c) {
            float4 o = { v[c * 4 + 0], v[c * 4 + 1], v[c * 4 + 2], v[c * 4 + 3] };
            *(float4*)(Xf + gf + c * 4) = o;
        }
        size_t gb = ((size_t)((wn + cg) >> 3)) * M8 + (size_t)m * 8;
        #pragma unroll
        for (int c = 0; c < 2; ++c) {
            uint4 o = { pk2bf(v[c*8+0], v[c*8+1]), pk2bf(v[c*8+2], v[c*8+3]),
                        pk2bf(v[c*8+4], v[c*8+5]), pk2bf(v[c*8+6], v[c*8+7]) };
            *(uint4*)(Xb + gb + (size_t)c * M8) = o;
        }
        asm volatile("" ::: "memory");
    }
}

// ------------------------------------------------------------- fused FFN ---
// X = LN2( GELU(X@W1^T + b1) @ W2^T + b2 + X ).  Block = 64 tokens, 4 waves.
// Hidden processed in 4 groups of 256: FFN1 -> H group in LDS -> FFN2 partial-K
// accumulate.  H never touches HBM.
__global__ __launch_bounds__(256, 2) void ffn_fused_kernel(
    const unsigned short* __restrict__ Xb, const unsigned short* __restrict__ W1b,
    const float* __restrict__ b1, const unsigned short* __restrict__ W2b,
    const float* __restrict__ b2, const float* __restrict__ resid,
    const float* __restrict__ lns, const float* __restrict__ lnb,
    float* __restrict__ XfOut, unsigned short* __restrict__ XbOut)
{
    __shared__ __align__(16) char smem[32768 + 17408 + 2048];
    unsigned short* Hs = (unsigned short*)smem;            // [32 kc][64 m][8]
    float* Ss = (float*)(smem + 32768 + 17408);            // [4][64]
    float* Sq = Ss + 256;

    const int tid = threadIdx.x;
    const int lane = tid & 63, wave = tid >> 6;
    const int l15 = lane & 15, quad = lane >> 4;
    const int wn = wave * 64;
    const int m0 = blockIdx.x * 64;
    const size_t w1step = 4 * (size_t)DFF * 8;   // 4 k-chunks of W1
    const size_t astep  = 4 * M8;
    float* Es = (float*)(smem + 32768 + wave * 4352);
    const int r16 = lane >> 2;
    const int cg  = (lane & 3) * 16;

    const unsigned short* ap[4];
    #pragma unroll
    for (int i = 0; i < 4; ++i)
        ap[i] = Xb + quad * M8 + (size_t)(m0 + i * 16 + l15) * 8;

    f32x4 acc2[4][4] = {};

    for (int g = 0; g < 4; ++g) {
        const int hbase = g * 256 + wn;          // this wave's H col base
        // ---- FFN1: acc1 = X @ W1^T for 64 x 64 tile (cols hbase..+63) ----
        const unsigned short* bp[4];
        #pragma unroll
        for (int j = 0; j < 4; ++j)
            bp[j] = W1b + quad * ((size_t)DFF * 8) + (size_t)(hbase + j * 16 + l15) * 8;

        f32x4 acc1[4][4] = {};
        bf16x8 aA[4], bA[4], aB[4], bB[4];
        #pragma unroll
        for (int i = 0; i < 4; ++i) aA[i] = *(const bf16x8*)(ap[i]);
        #pragma unroll
        for (int j = 0; j < 4; ++j) bA[j] = *(const bf16x8*)(bp[j]);
        for (int t = 0; t < 8; t += 2) {
            size_t o1 = (size_t)(t + 1);
            #pragma unroll
            for (int i = 0; i < 4; ++i) aB[i] = *(const bf16x8*)(ap[i] + o1 * astep);
            #pragma unroll
            for (int j = 0; j < 4; ++j) bB[j] = *(const bf16x8*)(bp[j] + o1 * w1step);
            #pragma unroll
            for (int i = 0; i < 4; ++i)
                #pragma unroll
                for (int j = 0; j < 4; ++j)
                    acc1[i][j] = __builtin_amdgcn_mfma_f32_16x16x32_bf16(
                        aA[i], bA[j], acc1[i][j], 0, 0, 0);
            size_t o2 = (size_t)((t + 2 < 8) ? t + 2 : 7);
            #pragma unroll
            for (int i = 0; i < 4; ++i) aA[i] = *(const bf16x8*)(ap[i] + o2 * astep);
            #pragma unroll
            for (int j = 0; j < 4; ++j) bA[j] = *(const bf16x8*)(bp[j] + o2 * w1step);
            #pragma unroll
            for (int i = 0; i < 4; ++i)
                #pragma unroll
                for (int j = 0; j < 4; ++j)
                    acc1[i][j] = __builtin_amdgcn_mfma_f32_16x16x32_bf16(
                        aB[i], bB[j], acc1[i][j], 0, 0, 0);
        }
        // ---- bias + GELU, transpose via Es, pack into Hs (FFN2-A layout) ----
        float b1j[4];
        #pragma unroll
        for (int j = 0; j < 4; ++j) b1j[j] = b1[hbase + j * 16 + l15];
        #pragma unroll
        for (int i = 0; i < 4; ++i) {
            #pragma unroll
            for (int j = 0; j < 4; ++j)
                #pragma unroll
                for (int r = 0; r < 4; ++r)
                    Es[(quad * 4 + r) * 68 + j * 16 + l15] =
                        gelu_fast(acc1[i][j][r] + b1j[j]);
            asm volatile("s_waitcnt lgkmcnt(0)" ::: "memory");
            int m = i * 16 + r16;
            float v[16];
            #pragma unroll
            for (int c = 0; c < 4; ++c) {
                f32x4 t = *(const f32x4*)&Es[r16 * 68 + cg + c * 4];
                v[c * 4 + 0] = t[0]; v[c * 4 + 1] = t[1];
                v[c * 4 + 2] = t[2]; v[c * 4 + 3] = t[3];
            }
            int kcl = (wn + cg) >> 3;   // local hidden chunk (this group)
            #pragma unroll
            for (int c = 0; c < 2; ++c) {
                uint4 o = { pk2bf(v[c*8+0], v[c*8+1]), pk2bf(v[c*8+2], v[c*8+3]),
                            pk2bf(v[c*8+4], v[c*8+5]), pk2bf(v[c*8+6], v[c*8+7]) };
                *(uint4*)(Hs + (size_t)(kcl + c) * 512 + (size_t)m * 8) = o;
            }
            asm volatile("" ::: "memory");
        }
        __syncthreads();   // Hs group complete (all waves)

        // ---- FFN2 partial: acc2 += H_g @ W2[:, k-slice g] ----
        #pragma unroll 2
        for (int tl = 0; tl < 8; ++tl) {
            int kcl = quad + 4 * tl;
            bf16x8 a2[4], bw2[4];
            #pragma unroll
            for (int i = 0; i < 4; ++i)
                a2[i] = *(const bf16x8*)(Hs + (size_t)kcl * 512 + (size_t)(i * 16 + l15) * 8);
            size_t kc2 = (size_t)(g * 32 + kcl);
            #pragma unroll
            for (int j = 0; j < 4; ++j)
                bw2[j] = *(const bf16x8*)(W2b + kc2 * ((size_t)DM * 8) +
                                          (size_t)(wn + j * 16 + l15) * 8);
            #pragma unroll
            for (int i = 0; i < 4; ++i)
                #pragma unroll
                for (int j = 0; j < 4; ++j)
                    acc2[i][j] = __builtin_amdgcn_mfma_f32_16x16x32_bf16(
                        a2[i], bw2[j], acc2[i][j], 0, 0, 0);
        }
        __syncthreads();   // before next group overwrites Hs
    }

    // ---- bias + resid + LN (gemm_ln epilogue) ----
    float bj[4], scj[4], bbj[4];
    #pragma unroll
    for (int j = 0; j < 4; ++j) {
        int col = wn + j * 16 + l15;
        bj[j] = b2[col]; scj[j] = lns[col]; bbj[j] = lnb[col];
    }
    #pragma unroll
    for (int i = 0; i < 4; ++i)
        #pragma unroll
        for (int r = 0; r < 4; ++r) {
            const float* rp = resid + (size_t)(m0 + i * 16 + quad * 4 + r) * DM + wn;
            #pragma unroll
            for (int j = 0; j < 4; ++j)
                acc2[i][j][r] += bj[j] + rp[j * 16 + l15];
        }
    #pragma unroll
    for (int i = 0; i < 4; ++i)
        #pragma unroll
        for (int r = 0; r < 4; ++r) {
            float s = 0.f, q = 0.f;
            #pragma unroll
            for (int j = 0; j < 4; ++j) {
                float x = acc2[i][j][r];
                s += x; q = fmaf(x, x, q);
            }
            #pragma unroll
            for (int off = 1; off < 16; off <<= 1) {
                s += __shfl_xor(s, off);
                q += __shfl_xor(q, off);
            }
            if (l15 == 0) {
                int row = i * 16 + quad * 4 + r;
                Ss[wave * 64 + row] = s;
                Sq[wave * 64 + row] = q;
            }
        }
    __syncthreads();
    #pragma unroll
    for (int i = 0; i < 4; ++i)
        #pragma unroll
        for (int r = 0; r < 4; ++r) {
            int row = i * 16 + quad * 4 + r;
            float s = Ss[row] + Ss[64 + row] + Ss[128 + row] + Ss[192 + row];
            float q = Sq[row] + Sq[64 + row] + Sq[128 + row] + Sq[192 + row];
            float mean = s * (1.0f / 256.0f);
            float var  = q * (1.0f / 256.0f) - mean * mean;
            float rinv = rsqrtf(var + 1e-5f);
            #pragma unroll
            for (int j = 0; j < 4; ++j)
                acc2[i][j][r] = (acc2[i][j][r] - mean) * rinv * scj[j] + bbj[j];
        }
    #pragma unroll
    for (int i = 0; i < 4; ++i) {
        #pragma unroll
        for (int j = 0; j < 4; ++j)
            #pragma unroll
            for (int r = 0; r < 4; ++r)
                Es[(quad * 4 + r) * 68 + j * 16 + l15] = acc2[i][j][r];
        asm volatile("s_waitcnt lgkmcnt(0)" ::: "memory");
        int m = m0 + i * 16 + r16;
        float v[16];
        #pragma unroll
        for (int c = 0; c < 4; ++c) {
            f32x4 t = *(const f32x4*)&Es[r16 * 68 + cg + c * 4];
            v[c * 4 + 0] = t[0]; v[c * 4 + 1] = t[1];
            v[c * 4 + 2] = t[2]; v[c * 4 + 3] = t[3];
        }
        size_t gf = (size_t)m * DM + wn + cg;
        #pragma unroll
        for (int c = 0; c < 4; ++c) {
            float4 o = { v[c * 4 + 0], v[c * 4 + 1], v[c * 4 + 2], v[c * 4 + 3] };
            *(float4*)(XfOut + gf + c * 4) = o;
        }
        size_t gb = ((size_t)((wn + cg) >> 3)) * M8 + (size_t)m * 8;
        #pragma unroll
        for (int c = 0; c < 2; ++c) {
            uint4 o = { pk2bf(v[c*8+0], v[c*8+1]), pk2bf(v[c*8+2], v[c*8+3]),
                        pk2bf(v[c*8+4], v[c*8+5]), pk2bf(v[c*8+6], v[c*8+7]) };
            *(uint4*)(XbOut + gb + (size_t)c * M8) = o;
        }
        asm volatile("" ::: "memory");
    }
}

// ------------------------------------------------------- MFMA attention ----
__global__ __launch_bounds__(64) void attn_mfma_kernel(
    const unsigned short* __restrict__ QKV, unsigned short* __restrict__ ATT)
{
    __shared__ __align__(16) char smem[22016];
    unsigned short* Qs = (unsigned short*)smem;           // [dc][t][8]
    unsigned short* Ks = (unsigned short*)(smem + 4096);
    unsigned short* VT = (unsigned short*)(smem + 8192);  // [d][t] pitch 72
    unsigned short* Ps = (unsigned short*)(smem + 12800); // [q][k] pitch 72
    float*          Po = (float*)(smem + 12800);          // [q][d] pitch 36

    const int wg = blockIdx.x, h = blockIdx.y;
    const int base = wg * WIN;
    const int lane = threadIdx.x;
    const int l15 = lane & 15, quad = lane >> 4;
    const float scale = 0.17677669529663687f;   // 1/sqrt(32)

    #pragma unroll
    for (int dc = 0; dc < 4; ++dc) {
        GLD_LDS16(QKV + ((size_t)(h * 4 + dc)) * M8 + (size_t)(base + lane) * 8,
                  Qs + dc * 512 + (size_t)lane * 8);
        GLD_LDS16(QKV + ((size_t)(32 + h * 4 + dc)) * M8 + (size_t)(base + lane) * 8,
                  Ks + dc * 512 + (size_t)lane * 8);
    }
    u16x8 vv[4];
    #pragma unroll
    for (int cc = 0; cc < 4; ++cc)
        vv[cc] = *(const u16x8*)(QKV + ((size_t)(64 + h * 4 + cc)) * M8 +
                                 (size_t)(base + lane) * 8);
    #pragma unroll
    for (int cc = 0; cc < 4; ++cc)
        #pragma unroll
        for (int e = 0; e < 8; ++e)
            VT[(cc * 8 + e) * 72 + lane] = vv[cc][e];
    __syncthreads();

    const f32x4 zero4 = {0.f, 0.f, 0.f, 0.f};
    bf16x8 aq[4], bk[4];
    #pragma unroll
    for (int i = 0; i < 4; ++i)
        aq[i] = *(const bf16x8*)(Qs + quad * 512 + (i * 16 + l15) * 8);
    #pragma unroll
    for (int j = 0; j < 4; ++j)
        bk[j] = *(const bf16x8*)(Ks + quad * 512 + (j * 16 + l15) * 8);
    f32x4 S[4][4];
    #pragma unroll
    for (int i = 0; i < 4; ++i)
        #pragma unroll
        for (int j = 0; j < 4; ++j)
            S[i][j] = __builtin_amdgcn_mfma_f32_16x16x32_bf16(aq[i], bk[j], zero4, 0, 0, 0);

    float mx[4][4], sum[4][4];
    #pragma unroll
    for (int i = 0; i < 4; ++i)
        #pragma unroll
        for (int r = 0; r < 4; ++r) {
            float m0 = -1e30f;
            #pragma unroll
            for (int j = 0; j < 4; ++j) {
                S[i][j][r] *= scale;
                m0 = fmaxf(m0, S[i][j][r]);
            }
            mx[i][r] = m0;
        }
    #pragma unroll
    for (int off = 1; off < 16; off <<= 1)
        #pragma unroll
        for (int i = 0; i < 4; ++i)
            #pragma unroll
            for (int r = 0; r < 4; ++r)
                mx[i][r] = fmaxf(mx[i][r], __shfl_xor(mx[i][r], off));
    #pragma unroll
    for (int i = 0; i < 4; ++i)
        #pragma unroll
        for (int r = 0; r < 4; ++r) {
            float s0 = 0.f;
            #pragma unroll
            for (int j = 0; j < 4; ++j) {
                float e = __expf(S[i][j][r] - mx[i][r]);
                S[i][j][r] = e;
                s0 += e;
            }
            sum[i][r] = s0;
        }
    #pragma unroll
    for (int off = 1; off < 16; off <<= 1)
        #pragma unroll
        for (int i = 0; i < 4; ++i)
            #pragma unroll
            for (int r = 0; r < 4; ++r)
                sum[i][r] += __shfl_xor(sum[i][r], off);

    #pragma unroll
    for (int i = 0; i < 4; ++i)
        #pragma unroll
        for (int r = 0; r < 4; ++r) {
            float inv = 1.0f / sum[i][r];
            #pragma unroll
            for (int j = 0; j < 4; ++j)
                Ps[(i * 16 + quad * 4 + r) * 72 + j * 16 + l15] =
                    f2bf(S[i][j][r] * inv);
        }
    asm volatile("s_waitcnt lgkmcnt(0)" ::: "memory");

    bf16x8 ap0[4], ap1[4], bv0[2], bv1[2];
    #pragma unroll
    for (int i = 0; i < 4; ++i) {
        ap0[i] = *(const bf16x8*)(Ps + (i * 16 + l15) * 72 + quad * 8);
        ap1[i] = *(const bf16x8*)(Ps + (i * 16 + l15) * 72 + 32 + quad * 8);
    }
    #pragma unroll
    for (int jd = 0; jd < 2; ++jd) {
        bv0[jd] = *(const bf16x8*)(VT + (jd * 16 + l15) * 72 + quad * 8);
        bv1[jd] = *(const bf16x8*)(VT + (jd * 16 + l15) * 72 + 32 + quad * 8);
    }
    f32x4 O[4][2];
    #pragma unroll
    for (int i = 0; i < 4; ++i)
        #pragma unroll
        for (int jd = 0; jd < 2; ++jd) {
            f32x4 t = __builtin_amdgcn_mfma_f32_16x16x32_bf16(ap0[i], bv0[jd], zero4, 0, 0, 0);
            O[i][jd] = __builtin_amdgcn_mfma_f32_16x16x32_bf16(ap1[i], bv1[jd], t, 0, 0, 0);
        }
    asm volatile("s_waitcnt lgkmcnt(0)" ::: "memory");

    #pragma unroll
    for (int i = 0; i < 4; ++i)
        #pragma unroll
        for (int jd = 0; jd < 2; ++jd)
            #pragma unroll
            for (int r = 0; r < 4; ++r)
                Po[(i * 16 + quad * 4 + r) * 36 + jd * 16 + l15] = O[i][jd][r];
    asm volatile("s_waitcnt lgkmcnt(0)" ::: "memory");

    #pragma unroll
    for (int g = 0; g < 4; ++g) {
        f32x4 t0 = *(const f32x4*)(Po + lane * 36 + g * 8);
        f32x4 t1 = *(const f32x4*)(Po + lane * 36 + g * 8 + 4);
        uint4 w = { pk2bf(t0[0], t0[1]), pk2bf(t0[2], t0[3]),
                    pk2bf(t1[0], t1[1]), pk2bf(t1[2], t1[3]) };
        *(uint4*)(ATT + ((size_t)(h * 4 + g)) * M8 + (size_t)(base + lane) * 8) = w;
    }
}

// ---------------------------------------------- final LN + transpose out ---
__global__ __launch_bounds__(256) void out_ln_kernel(
    const float* __restrict__ Xf, const float* __restrict__ sc,
    const float* __restrict__ bi, float* __restrict__ out)
{
    __shared__ float tile[64][257];
    __shared__ float mean_s[64], rinv_s[64];
    int b = blockIdx.y, l0 = blockIdx.x * 64;
    int tid = threadIdx.x, wave = tid >> 6, lane = tid & 63;
    int c = lane * 4;
    #pragma unroll
    for (int it = 0; it < 16; ++it) {
        int tl = wave * 16 + it;
        float4 v = *(const float4*)(Xf + ((size_t)(b * LSEQ + l0 + tl)) * DM + c);
        *(float4*)&tile[tl][c] = v;
        float sm = v.x + v.y + v.z + v.w;
        float sq = v.x * v.x + v.y * v.y + v.z * v.z + v.w * v.w;
        #pragma unroll
        for (int off = 32; off > 0; off >>= 1) {
            sm += __shfl_down(sm, off);
            sq += __shfl_down(sq, off);
        }
        if (lane == 0) {
            float mean = sm * (1.0f / 256.0f);
            float var  = sq * (1.0f / 256.0f) - mean * mean;
            mean_s[tl] = mean;
            rinv_s[tl] = rsqrtf(var + 1e-5f);
        }
    }
    __syncthreads();
    int lout = tid & 63, crow = tid >> 6;
    #pragma unroll
    for (int ct = 0; ct < 4; ++ct) {
        int c0 = ct * 64;
        #pragma unroll
        for (int it = 0; it < 16; ++it) {
            int cc = c0 + crow + it * 4;
            float v = tile[lout][cc];
            out[((size_t)(b * DM + cc)) * LSEQ + l0 + lout] =
                (v - mean_s[lout]) * rinv_s[lout] * sc[cc] + bi[cc];
        }
    }
}

// ----------------------------------------------------------------- driver --
extern "C" void kernel_launch(void* const* d_in, const int* in_sizes, int n_in,
                              void* d_out, int out_size, void* d_ws, size_t ws_size,
                              hipStream_t stream)
{
    const float* F   = (const float*)d_in[0];
    const float* Wi  = (const float*)d_in[1];
    const float* Bi  = (const float*)d_in[2];
    const float* Wo  = (const float*)d_in[3];
    const float* Bo  = (const float*)d_in[4];
    const float* W1  = (const float*)d_in[5];
    const float* B1  = (const float*)d_in[6];
    const float* W2  = (const float*)d_in[7];
    const float* B2  = (const float*)d_in[8];
    const float* L1s = (const float*)d_in[9];
    const float* L1b = (const float*)d_in[10];
    const float* L2s = (const float*)d_in[11];
    const float* L2b = (const float*)d_in[12];
    const float* Fs  = (const float*)d_in[13];
    const float* Fb  = (const float*)d_in[14];

    char* w = (char*)d_ws;
    float*          Xf   = (float*)w;                              // 33.5 MB
    unsigned short* QKVb = (unsigned short*)(w + 33554432);        // 50 MB
    unsigned short* Xb   = (unsigned short*)(w + 150994944);       // 16.8 MB
    unsigned short* ATTb = (unsigned short*)(w + 167772160);       // 16.8 MB
    unsigned short* WB   = (unsigned short*)(w + 184549376);       // 4.7 MB
    float*          PE   = (float*)(w + 189267968);                // 1 MB
    unsigned short* Wib  = WB;
    unsigned short* Wob  = WB + 589824;
    unsigned short* W1b  = WB + 786432;
    unsigned short* W2b  = WB + 1572864;

    cvt_kernel<<<(3 * 768 * 32 + 255) / 256, 256, 0, stream>>>(Wi, Wib, 768, 256, 3);
    cvt_kernel<<<(3 * 256 * 32 + 255) / 256, 256, 0, stream>>>(Wo, Wob, 256, 256, 3);
    cvt_kernel<<<(3 * 1024 * 32 + 255) / 256, 256, 0, stream>>>(W1, W1b, 1024, 256, 3);
    cvt_kernel<<<(3 * 256 * 128 + 255) / 256, 256, 0, stream>>>(W2, W2b, 256, 1024, 3);
    pe_kernel<<<LSEQ, 256, 0, stream>>>(PE);
    embed_kernel<<<dim3(DM / 64, LSEQ / 64, BSZ), 256, 0, stream>>>(F, PE, Xf, Xb);

    for (int i = 0; i < 3; ++i) {
        // QKV = X @ Wi^T + bi -> QKVb (k-chunk bf16)
        gemm_mfma_kernel<<<dim3(MTOK / 128, 768 / 128), 256, 0, stream>>>(
            Xb, Wib + (size_t)i * 196608, Bi + i * 768, QKVb, MTOK, 768, DM);
        // windowed MHA -> ATTb
        attn_mfma_kernel<<<dim3(BSZ * (LSEQ / WIN), NHEAD), 64, 0, stream>>>(QKVb, ATTb);
        // X = LN1( ATT @ Wo^T + bo + X ) -> Xf + Xb
        gemm_ln_kernel<<<MTOK / 64, 256, 0, stream>>>(
            ATTb, Wob + (size_t)i * 65536, Bo + i * DM, Xf,
            L1s + i * DM, L1b + i * DM, Xf, Xb, DM);
        // X = LN2( GELU(X@W1^T+b1)@W2^T + b2 + X )  (fully fused FFN)
        ffn_fused_kernel<<<MTOK / 64, 256, 0, stream>>>(
            Xb, W1b + (size_t)i * 262144, B1 + i * DFF,
            W2b + (size_t)i * 262144, B2 + i * DM, Xf,
            L2s + i * DM, L2b + i * DM, Xf, Xb);
    }

    out_ln_kernel<<<dim3(LSEQ / 64, BSZ), 256, 0, stream>>>(
        Xf, Fs, Fb, (float*)d_out);
}